// Round 6
// baseline (1736.469 us; speedup 1.0000x reference)
//
#include <hip/hip_runtime.h>
#include <hip/hip_bf16.h>
#include <cstdint>

typedef __attribute__((ext_vector_type(8))) short short8;
typedef __attribute__((ext_vector_type(4))) float float4v;

#define LOG2E 1.44269504088896340736f
#define LN2   0.69314718055994530942f

#if __has_builtin(__builtin_amdgcn_exp2f)
__device__ __forceinline__ float fexp2(float x){ return __builtin_amdgcn_exp2f(x); }
#else
__device__ __forceinline__ float fexp2(float x){ return exp2f(x); }
#endif
#if __has_builtin(__builtin_amdgcn_logf)
__device__ __forceinline__ float flog2(float x){ return __builtin_amdgcn_logf(x); }
#else
__device__ __forceinline__ float flog2(float x){ return log2f(x); }
#endif

// hhat = log2(1 + 2^zhat). With biases pre-scaled by log2e, a GEMM on hhat
// directly produces the next zhat (ln2 * log2e == 1 cancels).
__device__ __forceinline__ float softplus_hat(float zh){
  return flog2(1.0f + fexp2(zh));
}

// softplus output > 0 -> truncation (RTZ) to bf16 is a 1-instr shift.
__device__ __forceinline__ unsigned short bf16_trunc(float f){
  return (unsigned short)(__builtin_bit_cast(unsigned int, f) >> 16);
}

// ---------------------------------------------------------------------------
// Pre-pass: Wh [S,4,256,256] fp32 -> bf16 slabs Wt[s*4+l][kb][n][ki]
// (kb = k/32, ki = k%32). B-frags are read from GLOBAL: lanes {n,n+16,n+32,
// n+48} of a wave cover row n's 64B contiguously -> 1KB/wave-instr from L2.
// ---------------------------------------------------------------------------
__global__ void convert_wh(const float* __restrict__ Wh,
                           unsigned short* __restrict__ Wt){
  int e = blockIdx.x * 256 + threadIdx.x;          // 0 .. 2^21-1
  int n  = e & 255;
  int k  = (e >> 8) & 255;
  int sl = e >> 16;
  float v = Wh[e];
  __hip_bfloat16 h = __float2bfloat16(v);
  Wt[(sl << 16) + ((k >> 5) << 13) + (n << 5) + (k & 31)] =
      __builtin_bit_cast(unsigned short, h);
}

// ---------------------------------------------------------------------------
// Fused MLP. Round-4 structure (4 waves, wave tile 64m x 64n), but register-
// dieted to total <=128 regs (64 arch + 64 acc) via __launch_bounds__(256,4):
// 4 blocks/CU instead of 2. Rationale: round-4 counters showed 32% of cycles
// with NEITHER pipe issuing (MFMA 28 + VALU 40); the stall is B-load L2
// latency + barrier waits, and 164 total regs pinned us at 2 waves/SIMD.
// TLP replaces the lost prefetch ILP (m114 co-scheduling).
// ---------------------------------------------------------------------------
__global__ __launch_bounds__(256, 4) void series_mlp(
    const float* __restrict__ coords,
    const float* __restrict__ W0, const float* __restrict__ b0,
    const float* __restrict__ bh,
    const float* __restrict__ Wout, const float* __restrict__ bout,
    const unsigned short* __restrict__ Wt,
    float* __restrict__ out)
{
  __shared__ __align__(16) unsigned short h_lds[64 * 256];   // 32 KB
  __shared__ float cbuf[192];

  const int tid  = threadIdx.x;
  const int lane = tid & 63;
  const int wave = tid >> 6;          // wave owns cols [wave*64, +64), all 64 rows
  const int s    = blockIdx.y;
  const int m0   = blockIdx.x * 64;   // 3125*64 == 200000 exactly

  if (tid < 192) cbuf[tid] = coords[m0 * 3 + tid];
  __syncthreads();

  // ---------------- layer 0: K=3, pure VALU ----------------
  {
    const int c  = tid;
    const float w0 = W0[(s * 3 + 0) * 256 + c] * LOG2E;
    const float w1 = W0[(s * 3 + 1) * 256 + c] * LOG2E;
    const float w2 = W0[(s * 3 + 2) * 256 + c] * LOG2E;
    const float bb = b0[s * 256 + c] * LOG2E;
    const int cc = c >> 3, cl = c & 7;
    for (int m = 0; m < 64; ++m) {
      float zh = fmaf(cbuf[m * 3 + 2], w2,
                 fmaf(cbuf[m * 3 + 1], w1,
                 fmaf(cbuf[m * 3 + 0], w0, bb)));
      h_lds[m * 256 + ((cc ^ (m & 7)) << 3) + cl] = bf16_trunc(softplus_hat(zh));
    }
  }
  __syncthreads();

  const int colb = (wave << 6) + (lane & 15);
  const int q    = lane >> 4;

  // ---------------- hidden layers 0..2: MFMA 16x16x32 bf16 ----------------
  for (int l = 0; l < 3; ++l) {
    const unsigned short* slab = Wt + (((s << 2) + l) << 16);

    float bias[4];
    #pragma unroll
    for (int ni = 0; ni < 4; ++ni)
      bias[ni] = bh[((s << 2) + l) * 256 + colb + ni * 16] * LOG2E;

    float4v acc[4][4];
    #pragma unroll
    for (int mi = 0; mi < 4; ++mi)
      #pragma unroll
      for (int ni = 0; ni < 4; ++ni)
        acc[mi][ni] = (float4v){bias[ni], bias[ni], bias[ni], bias[ni]};

    const unsigned short* bbase = slab + (colb << 5) + (q << 3);

    #pragma unroll
    for (int kb = 0; kb < 8; ++kb) {
      short8 af[4], bf[4];
      #pragma unroll
      for (int ni = 0; ni < 4; ++ni)
        bf[ni] = *(const short8*)(bbase + (kb << 13) + (ni << 9));
      #pragma unroll
      for (int mi = 0; mi < 4; ++mi) {
        int m = mi * 16 + (lane & 15);
        int o = (kb << 2) + q;
        af[mi] = *(const short8*)&h_lds[m * 256 + ((o ^ (m & 7)) << 3)];
      }
      #pragma unroll
      for (int mi = 0; mi < 4; ++mi)
        #pragma unroll
        for (int ni = 0; ni < 4; ++ni)
          acc[mi][ni] = __builtin_amdgcn_mfma_f32_16x16x32_bf16(
              af[mi], bf[ni], acc[mi][ni], 0, 0, 0);
    }

    // softplus in regs BEFORE the barrier (overlaps other waves' MFMA tail)
    #pragma unroll
    for (int mi = 0; mi < 4; ++mi)
      #pragma unroll
      for (int ni = 0; ni < 4; ++ni) {
        float4v v = acc[mi][ni];
        #pragma unroll
        for (int r = 0; r < 4; ++r) v[r] = softplus_hat(v[r]);
        acc[mi][ni] = v;
      }

    __syncthreads();   // all A-reads of h done -> safe to overwrite

    #pragma unroll
    for (int mi = 0; mi < 4; ++mi) {
      #pragma unroll
      for (int ni = 0; ni < 4; ++ni) {
        float4v v = acc[mi][ni];
        int col = (wave << 6) + ni * 16 + (lane & 15);
        int cc = col >> 3, cl = col & 7;
        int mb = mi * 16 + (q << 2);
        #pragma unroll
        for (int r = 0; r < 4; ++r) {
          int m = mb + r;
          h_lds[m * 256 + ((cc ^ (m & 7)) << 3) + cl] = bf16_trunc(v[r]);
        }
      }
    }
    __syncthreads();   // h ready for next layer
  }

  // ------- layer 3: MFMA + fused output (dot with Wout, no h write-back) -------
  {
    const unsigned short* slab = Wt + (((s << 2) + 3) << 16);

    float bias[4];
    #pragma unroll
    for (int ni = 0; ni < 4; ++ni)
      bias[ni] = bh[((s << 2) + 3) * 256 + colb + ni * 16] * LOG2E;

    float4v acc[4][4];
    #pragma unroll
    for (int mi = 0; mi < 4; ++mi)
      #pragma unroll
      for (int ni = 0; ni < 4; ++ni)
        acc[mi][ni] = (float4v){bias[ni], bias[ni], bias[ni], bias[ni]};

    const unsigned short* bbase = slab + (colb << 5) + (q << 3);

    #pragma unroll
    for (int kb = 0; kb < 8; ++kb) {
      short8 af[4], bf[4];
      #pragma unroll
      for (int ni = 0; ni < 4; ++ni)
        bf[ni] = *(const short8*)(bbase + (kb << 13) + (ni << 9));
      #pragma unroll
      for (int mi = 0; mi < 4; ++mi) {
        int m = mi * 16 + (lane & 15);
        int o = (kb << 2) + q;
        af[mi] = *(const short8*)&h_lds[m * 256 + ((o ^ (m & 7)) << 3)];
      }
      #pragma unroll
      for (int mi = 0; mi < 4; ++mi)
        #pragma unroll
        for (int ni = 0; ni < 4; ++ni)
          acc[mi][ni] = __builtin_amdgcn_mfma_f32_16x16x32_bf16(
              af[mi], bf[ni], acc[mi][ni], 0, 0, 0);
    }

    // softplus + per-lane partial dot over this wave's 4 cols (fp32 h4).
    float wv[4];
    #pragma unroll
    for (int ni = 0; ni < 4; ++ni)
      wv[ni] = Wout[(s << 8) + colb + ni * 16];
    float p[16];
    #pragma unroll
    for (int i = 0; i < 16; ++i) p[i] = 0.f;
    #pragma unroll
    for (int mi = 0; mi < 4; ++mi)
      #pragma unroll
      for (int ni = 0; ni < 4; ++ni) {
        float4v v = acc[mi][ni];
        #pragma unroll
        for (int r = 0; r < 4; ++r)
          p[mi * 4 + r] = fmaf(softplus_hat(v[r]), wv[ni], p[mi * 4 + r]);
      }

    __syncthreads();                    // all A-reads done; h_lds reusable
    float* red = (float*)h_lds;         // 64 rows x 64 partials, stride 68 pad
    #pragma unroll
    for (int mi = 0; mi < 4; ++mi)
      #pragma unroll
      for (int r = 0; r < 4; ++r) {
        int row = mi * 16 + (q << 2) + r;
        red[row * 68 + (wave << 4) + (lane & 15)] = p[mi * 4 + r];
      }
    __syncthreads();

    if (tid < 64) {
      const float4v* rr = (const float4v*)&red[tid * 68];
      float4v a = rr[0];
      #pragma unroll
      for (int i = 1; i < 16; ++i) {
        float4v b = rr[i];
        a.x += b.x; a.y += b.y; a.z += b.z; a.w += b.w;
      }
      float tot = (a.x + a.y) + (a.z + a.w);
      out[(m0 + tid) * 8 + s] = fmaf(LN2, tot, bout[s]);  // undo log2-domain
    }
  }
}

// ---------------------------------------------------------------------------
// Fallback (scratch-free), fp32 VALU — only if ws_size < 4 MiB.
// ---------------------------------------------------------------------------
__global__ __launch_bounds__(256) void series_mlp_slow(
    const float* __restrict__ coords,
    const float* __restrict__ W0, const float* __restrict__ b0,
    const float* __restrict__ Wh, const float* __restrict__ bh,
    const float* __restrict__ Wout, const float* __restrict__ bout,
    float* __restrict__ out)
{
  __shared__ float h[64 * 256];
  __shared__ float cbuf[192];
  __shared__ float red[256];
  const int tid = threadIdx.x;
  const int s   = blockIdx.y;
  const int m0  = blockIdx.x * 64;

  if (tid < 192) cbuf[tid] = coords[m0 * 3 + tid];
  __syncthreads();
  {
    const float w0 = W0[(s * 3 + 0) * 256 + tid];
    const float w1 = W0[(s * 3 + 1) * 256 + tid];
    const float w2 = W0[(s * 3 + 2) * 256 + tid];
    const float bb = b0[s * 256 + tid];
    for (int m = 0; m < 64; ++m) {
      float z = fmaf(cbuf[m * 3 + 2], w2,
                fmaf(cbuf[m * 3 + 1], w1,
                fmaf(cbuf[m * 3 + 0], w0, bb)));
      h[m * 256 + tid] = LN2 * softplus_hat(z * LOG2E);
    }
  }
  __syncthreads();

  for (int l = 0; l < 4; ++l) {
    const float* W = Wh + (((s << 2) + l) << 16);
    const float bb = bh[((s << 2) + l) * 256 + tid];
    float acc[64];
    #pragma unroll
    for (int m = 0; m < 64; ++m) acc[m] = bb;
    for (int kc = 0; kc < 64; ++kc) {
      float w0 = W[(kc * 4 + 0) * 256 + tid];
      float w1 = W[(kc * 4 + 1) * 256 + tid];
      float w2 = W[(kc * 4 + 2) * 256 + tid];
      float w3 = W[(kc * 4 + 3) * 256 + tid];
      #pragma unroll
      for (int m = 0; m < 64; ++m) {
        float4v hv = *(const float4v*)&h[m * 256 + kc * 4];
        acc[m] = fmaf(hv.w, w3, fmaf(hv.z, w2,
                 fmaf(hv.y, w1, fmaf(hv.x, w0, acc[m]))));
      }
    }
    __syncthreads();
    #pragma unroll
    for (int m = 0; m < 64; ++m)
      h[m * 256 + tid] = LN2 * softplus_hat(acc[m] * LOG2E);
    __syncthreads();
  }
  {
    const int m = tid >> 2, qq = tid & 3;
    const float* wv = Wout + (s << 8);
    float sum = 0.f;
    for (int i = 0; i < 16; ++i) {
      int kk = (qq << 6) + ((((tid & 15) + i) << 2) & 63);
      float4v hv = *(const float4v*)&h[m * 256 + kk];
      sum += hv.x * wv[kk] + hv.y * wv[kk + 1] + hv.z * wv[kk + 2] + hv.w * wv[kk + 3];
    }
    red[tid] = sum;
    __syncthreads();
    if (tid < 64)
      out[(m0 + tid) * 8 + s] =
          red[tid * 4] + red[tid * 4 + 1] + red[tid * 4 + 2] + red[tid * 4 + 3] + bout[s];
  }
}

extern "C" void kernel_launch(void* const* d_in, const int* in_sizes, int n_in,
                              void* d_out, int out_size, void* d_ws, size_t ws_size,
                              hipStream_t stream) {
  const float* coords = (const float*)d_in[0];
  const float* W0     = (const float*)d_in[1];
  const float* b0     = (const float*)d_in[2];
  const float* Wh     = (const float*)d_in[3];
  const float* bh     = (const float*)d_in[4];
  const float* Wout   = (const float*)d_in[5];
  const float* bout   = (const float*)d_in[6];
  float* out = (float*)d_out;

  const size_t WT_BYTES = (size_t)8 * 4 * 256 * 256 * 2;   // 4 MiB bf16 slabs
  if (ws_size >= WT_BYTES) {
    unsigned short* Wt = (unsigned short*)d_ws;
    convert_wh<<<8192, 256, 0, stream>>>(Wh, Wt);
    series_mlp<<<dim3(3125, 8), dim3(256), 0, stream>>>(
        coords, W0, b0, bh, Wout, bout, Wt, out);
  } else {
    series_mlp_slow<<<dim3(3125, 8), dim3(256), 0, stream>>>(
        coords, W0, b0, Wh, bh, Wout, bout, out);
  }
  // second tuple output: echo coords
  hipMemcpyAsync(out + (size_t)200000 * 8, coords,
                 (size_t)200000 * 3 * sizeof(float),
                 hipMemcpyDeviceToDevice, stream);
}

// Round 7
// 1001.203 us; speedup vs baseline: 1.7344x; 1.7344x over previous
//
#include <hip/hip_runtime.h>
#include <hip/hip_bf16.h>
#include <cstdint>

typedef __attribute__((ext_vector_type(8))) short short8;
typedef __attribute__((ext_vector_type(4))) float float4v;

#define LOG2E 1.44269504088896340736f
#define LN2   0.69314718055994530942f

#if __has_builtin(__builtin_amdgcn_exp2f)
__device__ __forceinline__ float fexp2(float x){ return __builtin_amdgcn_exp2f(x); }
#else
__device__ __forceinline__ float fexp2(float x){ return exp2f(x); }
#endif
#if __has_builtin(__builtin_amdgcn_logf)
__device__ __forceinline__ float flog2(float x){ return __builtin_amdgcn_logf(x); }
#else
__device__ __forceinline__ float flog2(float x){ return log2f(x); }
#endif

// hhat = log2(1 + 2^zhat). With biases pre-scaled by log2e, a GEMM on hhat
// directly produces the next zhat (ln2 * log2e == 1 cancels).
__device__ __forceinline__ float softplus_hat(float zh){
  return flog2(1.0f + fexp2(zh));
}

// softplus output > 0 -> truncation (RTZ) to bf16 is a 1-instr shift.
__device__ __forceinline__ unsigned short bf16_trunc(float f){
  return (unsigned short)(__builtin_bit_cast(unsigned int, f) >> 16);
}

// ---------------------------------------------------------------------------
// Pre-pass: Wh [S,4,256,256] fp32 -> bf16 slabs Wt[s*4+l][kb][n][ki]
// (kb = k/32, ki = k%32). B-frags are read from GLOBAL: lanes {n,n+16,n+32,
// n+48} of a wave cover row n's 64B contiguously -> 1KB/wave-instr from L2.
// ---------------------------------------------------------------------------
__global__ void convert_wh(const float* __restrict__ Wh,
                           unsigned short* __restrict__ Wt){
  int e = blockIdx.x * 256 + threadIdx.x;          // 0 .. 2^21-1
  int n  = e & 255;
  int k  = (e >> 8) & 255;
  int sl = e >> 16;
  float v = Wh[e];
  __hip_bfloat16 h = __float2bfloat16(v);
  Wt[(sl << 16) + ((k >> 5) << 13) + (n << 5) + (k & 31)] =
      __builtin_bit_cast(unsigned short, h);
}

// ---------------------------------------------------------------------------
// One hidden layer's MFMA K-loop with explicit deep register pipelining:
//  * bq[3][4]: rotating 3-slot B prefetch (48 VGPR) — B for kb,kb+1,kb+2
//    always in flight, covering ~250cyc L2 latency with ~3 MFMA bursts.
//  * a0/a1: double-buffered A ds_reads (32 VGPR).
// Occupancy unchanged (2 blocks/CU band reaches up to 256 total regs);
// round-6 proved going below 128 regs spills, so we spend the free headroom
// on ILP instead.
// ---------------------------------------------------------------------------
__device__ __forceinline__ void layer_mfma(
    const unsigned short* __restrict__ slab,
    const unsigned short* __restrict__ h_lds,
    int lane, int colb, int q, float4v acc[4][4])
{
  const unsigned short* bbase = slab + (colb << 5) + (q << 3);

  short8 bq[3][4];
  #pragma unroll
  for (int i = 0; i < 3; ++i)
    #pragma unroll
    for (int ni = 0; ni < 4; ++ni)
      bq[i][ni] = *(const short8*)(bbase + (i << 13) + (ni << 9));

  short8 a0[4], a1[4];
  #pragma unroll
  for (int mi = 0; mi < 4; ++mi) {
    int m = mi * 16 + (lane & 15);
    a0[mi] = *(const short8*)&h_lds[m * 256 + ((q ^ (m & 7)) << 3)];
  }

  #pragma unroll
  for (int kb = 0; kb < 8; ++kb) {
    short8* cur = (kb & 1) ? a1 : a0;
    short8* nxt = (kb & 1) ? a0 : a1;
    if (kb < 7) {                      // A prefetch depth 1 (LDS)
      #pragma unroll
      for (int mi = 0; mi < 4; ++mi) {
        int m = mi * 16 + (lane & 15);
        int o = ((kb + 1) << 2) + q;
        nxt[mi] = *(const short8*)&h_lds[m * 256 + ((o ^ (m & 7)) << 3)];
      }
    }
    #pragma unroll
    for (int mi = 0; mi < 4; ++mi)
      #pragma unroll
      for (int ni = 0; ni < 4; ++ni)
        acc[mi][ni] = __builtin_amdgcn_mfma_f32_16x16x32_bf16(
            cur[mi], bq[kb % 3][ni], acc[mi][ni], 0, 0, 0);
    if (kb + 3 < 8) {                  // B prefetch depth 3 (global/L2)
      #pragma unroll
      for (int ni = 0; ni < 4; ++ni)
        bq[kb % 3][ni] = *(const short8*)(bbase + ((kb + 3) << 13) + (ni << 9));
    }
  }
}

// ---------------------------------------------------------------------------
// Fused MLP. Round-4 structure (4 waves, wave tile 64m x 64n, 2 blocks/CU)
// + deep register pipelining (layer_mfma) + XCD-aware swizzle: flat grid,
// s = blockIdx.x & 7 -> round-robin dispatch pins each series to one XCD, so
// each XCD's L2 holds only its series' 512KB slab (vs 4MB = whole L2 before).
// ---------------------------------------------------------------------------
__global__ __launch_bounds__(256, 2) void series_mlp(
    const float* __restrict__ coords,
    const float* __restrict__ W0, const float* __restrict__ b0,
    const float* __restrict__ bh,
    const float* __restrict__ Wout, const float* __restrict__ bout,
    const unsigned short* __restrict__ Wt,
    float* __restrict__ out)
{
  __shared__ __align__(16) unsigned short h_lds[64 * 256];   // 32 KB
  __shared__ float cbuf[192];

  const int tid  = threadIdx.x;
  const int lane = tid & 63;
  const int wave = tid >> 6;          // wave owns cols [wave*64, +64), all 64 rows
  const int s    = blockIdx.x & 7;    // series == XCD (round-robin dispatch)
  const int m0   = (blockIdx.x >> 3) * 64;   // 3125*64 == 200000 exactly

  if (tid < 192) cbuf[tid] = coords[m0 * 3 + tid];
  __syncthreads();

  // ---------------- layer 0: K=3, pure VALU ----------------
  {
    const int c  = tid;
    const float w0 = W0[(s * 3 + 0) * 256 + c] * LOG2E;
    const float w1 = W0[(s * 3 + 1) * 256 + c] * LOG2E;
    const float w2 = W0[(s * 3 + 2) * 256 + c] * LOG2E;
    const float bb = b0[s * 256 + c] * LOG2E;
    const int cc = c >> 3, cl = c & 7;
    for (int m = 0; m < 64; ++m) {
      float zh = fmaf(cbuf[m * 3 + 2], w2,
                 fmaf(cbuf[m * 3 + 1], w1,
                 fmaf(cbuf[m * 3 + 0], w0, bb)));
      h_lds[m * 256 + ((cc ^ (m & 7)) << 3) + cl] = bf16_trunc(softplus_hat(zh));
    }
  }
  __syncthreads();

  const int colb = (wave << 6) + (lane & 15);
  const int q    = lane >> 4;

  // ---------------- hidden layers 0..2: MFMA 16x16x32 bf16 ----------------
  #pragma unroll
  for (int l = 0; l < 3; ++l) {
    const unsigned short* slab = Wt + (((s << 2) + l) << 16);

    float bias[4];
    #pragma unroll
    for (int ni = 0; ni < 4; ++ni)
      bias[ni] = bh[((s << 2) + l) * 256 + colb + ni * 16] * LOG2E;

    float4v acc[4][4];
    #pragma unroll
    for (int mi = 0; mi < 4; ++mi)
      #pragma unroll
      for (int ni = 0; ni < 4; ++ni)
        acc[mi][ni] = (float4v){bias[ni], bias[ni], bias[ni], bias[ni]};

    layer_mfma(slab, h_lds, lane, colb, q, acc);

    // softplus in regs BEFORE the barrier (overlaps other waves' MFMA tail)
    #pragma unroll
    for (int mi = 0; mi < 4; ++mi)
      #pragma unroll
      for (int ni = 0; ni < 4; ++ni) {
        float4v v = acc[mi][ni];
        #pragma unroll
        for (int r = 0; r < 4; ++r) v[r] = softplus_hat(v[r]);
        acc[mi][ni] = v;
      }

    __syncthreads();   // all A-reads of h done -> safe to overwrite

    #pragma unroll
    for (int mi = 0; mi < 4; ++mi) {
      #pragma unroll
      for (int ni = 0; ni < 4; ++ni) {
        float4v v = acc[mi][ni];
        int col = (wave << 6) + ni * 16 + (lane & 15);
        int cc = col >> 3, cl = col & 7;
        int mb = mi * 16 + (q << 2);
        #pragma unroll
        for (int r = 0; r < 4; ++r) {
          int m = mb + r;
          h_lds[m * 256 + ((cc ^ (m & 7)) << 3) + cl] = bf16_trunc(v[r]);
        }
      }
    }
    __syncthreads();   // h ready for next layer
  }

  // ------- layer 3: MFMA + fused output (dot with Wout, no h write-back) -------
  {
    const unsigned short* slab = Wt + (((s << 2) + 3) << 16);

    float bias[4];
    #pragma unroll
    for (int ni = 0; ni < 4; ++ni)
      bias[ni] = bh[((s << 2) + 3) * 256 + colb + ni * 16] * LOG2E;

    float4v acc[4][4];
    #pragma unroll
    for (int mi = 0; mi < 4; ++mi)
      #pragma unroll
      for (int ni = 0; ni < 4; ++ni)
        acc[mi][ni] = (float4v){bias[ni], bias[ni], bias[ni], bias[ni]};

    layer_mfma(slab, h_lds, lane, colb, q, acc);

    // softplus + per-lane partial dot over this wave's 4 cols (fp32 h4).
    float wv[4];
    #pragma unroll
    for (int ni = 0; ni < 4; ++ni)
      wv[ni] = Wout[(s << 8) + colb + ni * 16];
    float p[16];
    #pragma unroll
    for (int i = 0; i < 16; ++i) p[i] = 0.f;
    #pragma unroll
    for (int mi = 0; mi < 4; ++mi)
      #pragma unroll
      for (int ni = 0; ni < 4; ++ni) {
        float4v v = acc[mi][ni];
        #pragma unroll
        for (int r = 0; r < 4; ++r)
          p[mi * 4 + r] = fmaf(softplus_hat(v[r]), wv[ni], p[mi * 4 + r]);
      }

    __syncthreads();                    // all A-reads done; h_lds reusable
    float* red = (float*)h_lds;         // 64 rows x 64 partials, stride 68 pad
    #pragma unroll
    for (int mi = 0; mi < 4; ++mi)
      #pragma unroll
      for (int r = 0; r < 4; ++r) {
        int row = mi * 16 + (q << 2) + r;
        red[row * 68 + (wave << 4) + (lane & 15)] = p[mi * 4 + r];
      }
    __syncthreads();

    if (tid < 64) {
      const float4v* rr = (const float4v*)&red[tid * 68];
      float4v a = rr[0];
      #pragma unroll
      for (int i = 1; i < 16; ++i) {
        float4v b = rr[i];
        a.x += b.x; a.y += b.y; a.z += b.z; a.w += b.w;
      }
      float tot = (a.x + a.y) + (a.z + a.w);
      out[(m0 + tid) * 8 + s] = fmaf(LN2, tot, bout[s]);  // undo log2-domain
    }
  }
}

// ---------------------------------------------------------------------------
// Fallback (scratch-free), fp32 VALU — only if ws_size < 4 MiB.
// ---------------------------------------------------------------------------
__global__ __launch_bounds__(256) void series_mlp_slow(
    const float* __restrict__ coords,
    const float* __restrict__ W0, const float* __restrict__ b0,
    const float* __restrict__ Wh, const float* __restrict__ bh,
    const float* __restrict__ Wout, const float* __restrict__ bout,
    float* __restrict__ out)
{
  __shared__ float h[64 * 256];
  __shared__ float cbuf[192];
  __shared__ float red[256];
  const int tid = threadIdx.x;
  const int s   = blockIdx.y;
  const int m0  = blockIdx.x * 64;

  if (tid < 192) cbuf[tid] = coords[m0 * 3 + tid];
  __syncthreads();
  {
    const float w0 = W0[(s * 3 + 0) * 256 + tid];
    const float w1 = W0[(s * 3 + 1) * 256 + tid];
    const float w2 = W0[(s * 3 + 2) * 256 + tid];
    const float bb = b0[s * 256 + tid];
    for (int m = 0; m < 64; ++m) {
      float z = fmaf(cbuf[m * 3 + 2], w2,
                fmaf(cbuf[m * 3 + 1], w1,
                fmaf(cbuf[m * 3 + 0], w0, bb)));
      h[m * 256 + tid] = LN2 * softplus_hat(z * LOG2E);
    }
  }
  __syncthreads();

  for (int l = 0; l < 4; ++l) {
    const float* W = Wh + (((s << 2) + l) << 16);
    const float bb = bh[((s << 2) + l) * 256 + tid];
    float acc[64];
    #pragma unroll
    for (int m = 0; m < 64; ++m) acc[m] = bb;
    for (int kc = 0; kc < 64; ++kc) {
      float w0 = W[(kc * 4 + 0) * 256 + tid];
      float w1 = W[(kc * 4 + 1) * 256 + tid];
      float w2 = W[(kc * 4 + 2) * 256 + tid];
      float w3 = W[(kc * 4 + 3) * 256 + tid];
      #pragma unroll
      for (int m = 0; m < 64; ++m) {
        float4v hv = *(const float4v*)&h[m * 256 + kc * 4];
        acc[m] = fmaf(hv.w, w3, fmaf(hv.z, w2,
                 fmaf(hv.y, w1, fmaf(hv.x, w0, acc[m]))));
      }
    }
    __syncthreads();
    #pragma unroll
    for (int m = 0; m < 64; ++m)
      h[m * 256 + tid] = LN2 * softplus_hat(acc[m] * LOG2E);
    __syncthreads();
  }
  {
    const int m = tid >> 2, qq = tid & 3;
    const float* wv = Wout + (s << 8);
    float sum = 0.f;
    for (int i = 0; i < 16; ++i) {
      int kk = (qq << 6) + ((((tid & 15) + i) << 2) & 63);
      float4v hv = *(const float4v*)&h[m * 256 + kk];
      sum += hv.x * wv[kk] + hv.y * wv[kk + 1] + hv.z * wv[kk + 2] + hv.w * wv[kk + 3];
    }
    red[tid] = sum;
    __syncthreads();
    if (tid < 64)
      out[(m0 + tid) * 8 + s] =
          red[tid * 4] + red[tid * 4 + 1] + red[tid * 4 + 2] + red[tid * 4 + 3] + bout[s];
  }
}

extern "C" void kernel_launch(void* const* d_in, const int* in_sizes, int n_in,
                              void* d_out, int out_size, void* d_ws, size_t ws_size,
                              hipStream_t stream) {
  const float* coords = (const float*)d_in[0];
  const float* W0     = (const float*)d_in[1];
  const float* b0     = (const float*)d_in[2];
  const float* Wh     = (const float*)d_in[3];
  const float* bh     = (const float*)d_in[4];
  const float* Wout   = (const float*)d_in[5];
  const float* bout   = (const float*)d_in[6];
  float* out = (float*)d_out;

  const size_t WT_BYTES = (size_t)8 * 4 * 256 * 256 * 2;   // 4 MiB bf16 slabs
  if (ws_size >= WT_BYTES) {
    unsigned short* Wt = (unsigned short*)d_ws;
    convert_wh<<<8192, 256, 0, stream>>>(Wh, Wt);
    series_mlp<<<dim3(25000), dim3(256), 0, stream>>>(
        coords, W0, b0, bh, Wout, bout, Wt, out);
  } else {
    series_mlp_slow<<<dim3(3125, 8), dim3(256), 0, stream>>>(
        coords, W0, b0, Wh, bh, Wout, bout, out);
  }
  // second tuple output: echo coords
  hipMemcpyAsync(out + (size_t)200000 * 8, coords,
                 (size_t)200000 * 3 * sizeof(float),
                 hipMemcpyDeviceToDevice, stream);
}

// Round 8
// 915.964 us; speedup vs baseline: 1.8958x; 1.0931x over previous
//
#include <hip/hip_runtime.h>
#include <hip/hip_bf16.h>
#include <cstdint>

typedef __attribute__((ext_vector_type(8))) short short8;
typedef __attribute__((ext_vector_type(4))) float float4v;

#define LOG2E 1.44269504088896340736f
#define LN2   0.69314718055994530942f

#if __has_builtin(__builtin_amdgcn_exp2f)
__device__ __forceinline__ float fexp2(float x){ return __builtin_amdgcn_exp2f(x); }
#else
__device__ __forceinline__ float fexp2(float x){ return exp2f(x); }
#endif
#if __has_builtin(__builtin_amdgcn_logf)
__device__ __forceinline__ float flog2(float x){ return __builtin_amdgcn_logf(x); }
#else
__device__ __forceinline__ float flog2(float x){ return log2f(x); }
#endif

// hhat = log2(1 + 2^zhat); biases pre-scaled by log2e so GEMM on hhat yields
// the next zhat directly (ln2 * log2e == 1 cancels).
__device__ __forceinline__ float softplus_hat(float zh){
  return flog2(1.0f + fexp2(zh));
}

// softplus output > 0 -> truncation (RTZ) to bf16 is a 1-instr shift.
__device__ __forceinline__ unsigned short bf16_trunc(float f){
  return (unsigned short)(__builtin_bit_cast(unsigned int, f) >> 16);
}

#define HSTRIDE 264   // h row stride in elems: 264*2B=528B -> 2-way bank alias (free)

// ---------------------------------------------------------------------------
// Pre-pass: Wh [S,4,256,256] fp32 -> bf16 slabs Wt[s*4+l][kb][n][ki]
// (kb = k/32, ki = k%32). B-frags read from GLOBAL: lanes {n,n+16,n+32,n+48}
// cover row n's 64B contiguously -> 1KB/wave-instr from L2.
// ---------------------------------------------------------------------------
__global__ void convert_wh(const float* __restrict__ Wh,
                           unsigned short* __restrict__ Wt){
  int e = blockIdx.x * 256 + threadIdx.x;          // 0 .. 2^21-1
  int n  = e & 255;
  int k  = (e >> 8) & 255;
  int sl = e >> 16;
  float v = Wh[e];
  __hip_bfloat16 h = __float2bfloat16(v);
  Wt[(sl << 16) + ((k >> 5) << 13) + (n << 5) + (k & 31)] =
      __builtin_bit_cast(unsigned short, h);
}

__device__ __forceinline__ float4v bf16_mfma(short8 a, short8 b, float4v c){
  return __builtin_amdgcn_mfma_f32_16x16x32_bf16(a, b, c, 0, 0, 0);
}

// ---------------------------------------------------------------------------
// One hidden layer's K-loop. Rotating 3-slot B prefetch with CONTINUOUS phase
// (slot = (8L+kb)%3, compile-time under full unroll): at kb=5..7 the freed
// slot prefetches the NEXT layer's kb 0..2 — global loads have no barrier
// dependency, so they fly during the epilogue+barrier (no per-layer refill
// stall). A double-buffered from LDS with pure-immediate offsets.
// ---------------------------------------------------------------------------
template<int L>
__device__ __forceinline__ void hidden_mfma(
    const unsigned short* __restrict__ bbase0,   // slab base + lane offset
    const unsigned short* __restrict__ aptr,     // h_lds + lane A-base
    short8 (&bq)[3][4], float4v (&acc)[4][4])
{
  const unsigned short* bb = bbase0 + L * 65536;
  const unsigned short* bn = bbase0 + (L + 1) * 65536;

  short8 a0[4], a1[4];
  #pragma unroll
  for (int mi = 0; mi < 4; ++mi)
    a0[mi] = *(const short8*)(aptr + mi * 4224);          // imm: mi*8448B

  #pragma unroll
  for (int kb = 0; kb < 8; ++kb) {
    short8* cur = (kb & 1) ? a1 : a0;
    short8* nxt = (kb & 1) ? a0 : a1;
    if (kb < 7) {                                          // A prefetch (LDS)
      #pragma unroll
      for (int mi = 0; mi < 4; ++mi)
        nxt[mi] = *(const short8*)(aptr + mi * 4224 + (kb + 1) * 32);
    }
    const int slot = (8 * L + kb) % 3;                     // compile-time
    #pragma unroll
    for (int mi = 0; mi < 4; ++mi)
      #pragma unroll
      for (int ni = 0; ni < 4; ++ni)
        acc[mi][ni] = bf16_mfma(cur[mi], bq[slot][ni], acc[mi][ni]);
    if (kb < 5) {                                          // B depth-3, this layer
      #pragma unroll
      for (int ni = 0; ni < 4; ++ni)
        bq[slot][ni] = *(const short8*)(bb + (kb + 3) * 8192 + ni * 512);
    } else if (L < 3) {                                    // next layer's kb 0..2
      #pragma unroll
      for (int ni = 0; ni < 4; ++ni)
        bq[slot][ni] = *(const short8*)(bn + (kb - 5) * 8192 + ni * 512);
    }
  }
}

// ---------------------------------------------------------------------------
// Fused MLP: 4 waves, wave tile 64m x 64n, one series per block,
// s = blockIdx.x & 7 (XCD-pinned weight slabs). h in LDS with stride-264
// padding: all LDS addressing is one base reg + immediate (no XOR VALU).
// ---------------------------------------------------------------------------
__global__ __launch_bounds__(256, 2) void series_mlp(
    const float* __restrict__ coords,
    const float* __restrict__ W0, const float* __restrict__ b0,
    const float* __restrict__ bh,
    const float* __restrict__ Wout, const float* __restrict__ bout,
    const unsigned short* __restrict__ Wt,
    float* __restrict__ out)
{
  __shared__ __align__(16) unsigned short h_lds[64 * HSTRIDE];   // 33792 B
  __shared__ float cbuf[192];

  const int tid  = threadIdx.x;
  const int lane = tid & 63;
  const int wave = tid >> 6;
  const int s    = blockIdx.x & 7;          // series == XCD
  const int m0   = (blockIdx.x >> 3) * 64;  // 3125*64 == 200000 exactly

  if (tid < 192) cbuf[tid] = coords[m0 * 3 + tid];
  __syncthreads();

  // ---------------- layer 0: K=3, pure VALU, float4 coord reads ----------------
  {
    const int c  = tid;
    const float w0 = W0[(s * 3 + 0) * 256 + c] * LOG2E;
    const float w1 = W0[(s * 3 + 1) * 256 + c] * LOG2E;
    const float w2 = W0[(s * 3 + 2) * 256 + c] * LOG2E;
    const float bb = b0[s * 256 + c] * LOG2E;
    const float4v* c4 = (const float4v*)cbuf;
    #pragma unroll
    for (int j = 0; j < 16; ++j) {             // 4 rows per iter, 3 b128 reads
      float4v x0 = c4[j * 3 + 0];
      float4v x1 = c4[j * 3 + 1];
      float4v x2 = c4[j * 3 + 2];
      float z0 = fmaf(x0.z, w2, fmaf(x0.y, w1, fmaf(x0.x, w0, bb)));
      float z1 = fmaf(x1.y, w2, fmaf(x1.x, w1, fmaf(x0.w, w0, bb)));
      float z2 = fmaf(x2.x, w2, fmaf(x1.w, w1, fmaf(x1.z, w0, bb)));
      float z3 = fmaf(x2.w, w2, fmaf(x2.z, w1, fmaf(x2.y, w0, bb)));
      h_lds[(4 * j + 0) * HSTRIDE + c] = bf16_trunc(softplus_hat(z0));
      h_lds[(4 * j + 1) * HSTRIDE + c] = bf16_trunc(softplus_hat(z1));
      h_lds[(4 * j + 2) * HSTRIDE + c] = bf16_trunc(softplus_hat(z2));
      h_lds[(4 * j + 3) * HSTRIDE + c] = bf16_trunc(softplus_hat(z3));
    }
  }
  __syncthreads();

  const int colb = (wave << 6) + (lane & 15);
  const int q    = lane >> 4;
  // A-frag lane base: row (lane&15), octet q. Imm: mi*4224 + kb*32 elems.
  const unsigned short* aptr = h_lds + (lane & 15) * HSTRIDE + q * 8;
  // C-write lane base: row q*4, col colb. Imm: mi*4224 + r*264 + ni*16 elems.
  unsigned short* cptr = h_lds + (q * 4) * HSTRIDE + colb;

  const unsigned short* bbase0 = Wt + ((s << 2) << 16) + (colb << 5) + (q << 3);

  short8 bq[3][4];
  #pragma unroll
  for (int i = 0; i < 3; ++i)
    #pragma unroll
    for (int ni = 0; ni < 4; ++ni)
      bq[i][ni] = *(const short8*)(bbase0 + i * 8192 + ni * 512);

  float4v acc[4][4];

  // ---------------- hidden layers 0..2 ----------------
  #define HIDDEN_LAYER(L)                                                     \
  {                                                                           \
    float bias[4];                                                            \
    _Pragma("unroll")                                                         \
    for (int ni = 0; ni < 4; ++ni)                                            \
      bias[ni] = bh[((s << 2) + L) * 256 + colb + ni * 16] * LOG2E;           \
    _Pragma("unroll")                                                         \
    for (int mi = 0; mi < 4; ++mi)                                            \
      _Pragma("unroll")                                                       \
      for (int ni = 0; ni < 4; ++ni)                                          \
        acc[mi][ni] = (float4v){bias[ni], bias[ni], bias[ni], bias[ni]};      \
    hidden_mfma<L>(bbase0, aptr, bq, acc);                                    \
    _Pragma("unroll")                                                         \
    for (int mi = 0; mi < 4; ++mi)                                            \
      _Pragma("unroll")                                                       \
      for (int ni = 0; ni < 4; ++ni) {                                        \
        float4v v = acc[mi][ni];                                              \
        _Pragma("unroll")                                                     \
        for (int r = 0; r < 4; ++r) v[r] = softplus_hat(v[r]);                \
        acc[mi][ni] = v;                                                      \
      }                                                                       \
    __syncthreads();                                                          \
    _Pragma("unroll")                                                         \
    for (int mi = 0; mi < 4; ++mi)                                            \
      _Pragma("unroll")                                                       \
      for (int ni = 0; ni < 4; ++ni) {                                        \
        float4v v = acc[mi][ni];                                              \
        _Pragma("unroll")                                                     \
        for (int r = 0; r < 4; ++r)                                           \
          cptr[mi * 4224 + r * HSTRIDE + ni * 16] = bf16_trunc(v[r]);         \
      }                                                                       \
    __syncthreads();                                                          \
  }

  HIDDEN_LAYER(0)
  HIDDEN_LAYER(1)
  HIDDEN_LAYER(2)
  #undef HIDDEN_LAYER

  // ------- layer 3: MFMA + fused output (dot with Wout, no h write-back) -------
  {
    float bias[4];
    #pragma unroll
    for (int ni = 0; ni < 4; ++ni)
      bias[ni] = bh[((s << 2) + 3) * 256 + colb + ni * 16] * LOG2E;
    #pragma unroll
    for (int mi = 0; mi < 4; ++mi)
      #pragma unroll
      for (int ni = 0; ni < 4; ++ni)
        acc[mi][ni] = (float4v){bias[ni], bias[ni], bias[ni], bias[ni]};

    hidden_mfma<3>(bbase0, aptr, bq, acc);

    // softplus + per-lane partial dot over this wave's 4 cols (fp32 h4)
    float wv[4];
    #pragma unroll
    for (int ni = 0; ni < 4; ++ni)
      wv[ni] = Wout[(s << 8) + colb + ni * 16];
    float p[16];
    #pragma unroll
    for (int i = 0; i < 16; ++i) p[i] = 0.f;
    #pragma unroll
    for (int mi = 0; mi < 4; ++mi)
      #pragma unroll
      for (int ni = 0; ni < 4; ++ni) {
        float4v v = acc[mi][ni];
        #pragma unroll
        for (int r = 0; r < 4; ++r)
          p[mi * 4 + r] = fmaf(softplus_hat(v[r]), wv[ni], p[mi * 4 + r]);
      }

    __syncthreads();                    // all A-reads done; h_lds reusable
    float* red = (float*)h_lds;         // 64 rows x 64 partials, stride-68 pad
    #pragma unroll
    for (int mi = 0; mi < 4; ++mi)
      #pragma unroll
      for (int r = 0; r < 4; ++r) {
        int row = mi * 16 + (q << 2) + r;
        red[row * 68 + (wave << 4) + (lane & 15)] = p[mi * 4 + r];
      }
    __syncthreads();

    if (tid < 64) {
      const float4v* rr = (const float4v*)&red[tid * 68];
      float4v a = rr[0];
      #pragma unroll
      for (int i = 1; i < 16; ++i) {
        float4v b = rr[i];
        a.x += b.x; a.y += b.y; a.z += b.z; a.w += b.w;
      }
      float tot = (a.x + a.y) + (a.z + a.w);
      out[(m0 + tid) * 8 + s] = fmaf(LN2, tot, bout[s]);  // undo log2-domain
    }
  }
}

// ---------------------------------------------------------------------------
// Fallback (scratch-free), fp32 VALU — only if ws_size < 4 MiB.
// ---------------------------------------------------------------------------
__global__ __launch_bounds__(256) void series_mlp_slow(
    const float* __restrict__ coords,
    const float* __restrict__ W0, const float* __restrict__ b0,
    const float* __restrict__ Wh, const float* __restrict__ bh,
    const float* __restrict__ Wout, const float* __restrict__ bout,
    float* __restrict__ out)
{
  __shared__ float h[64 * 256];
  __shared__ float cbuf[192];
  __shared__ float red[256];
  const int tid = threadIdx.x;
  const int s   = blockIdx.y;
  const int m0  = blockIdx.x * 64;

  if (tid < 192) cbuf[tid] = coords[m0 * 3 + tid];
  __syncthreads();
  {
    const float w0 = W0[(s * 3 + 0) * 256 + tid];
    const float w1 = W0[(s * 3 + 1) * 256 + tid];
    const float w2 = W0[(s * 3 + 2) * 256 + tid];
    const float bb = b0[s * 256 + tid];
    for (int m = 0; m < 64; ++m) {
      float z = fmaf(cbuf[m * 3 + 2], w2,
                fmaf(cbuf[m * 3 + 1], w1,
                fmaf(cbuf[m * 3 + 0], w0, bb)));
      h[m * 256 + tid] = LN2 * softplus_hat(z * LOG2E);
    }
  }
  __syncthreads();

  for (int l = 0; l < 4; ++l) {
    const float* W = Wh + (((s << 2) + l) << 16);
    const float bb = bh[((s << 2) + l) * 256 + tid];
    float acc[64];
    #pragma unroll
    for (int m = 0; m < 64; ++m) acc[m] = bb;
    for (int kc = 0; kc < 64; ++kc) {
      float w0 = W[(kc * 4 + 0) * 256 + tid];
      float w1 = W[(kc * 4 + 1) * 256 + tid];
      float w2 = W[(kc * 4 + 2) * 256 + tid];
      float w3 = W[(kc * 4 + 3) * 256 + tid];
      #pragma unroll
      for (int m = 0; m < 64; ++m) {
        float4v hv = *(const float4v*)&h[m * 256 + kc * 4];
        acc[m] = fmaf(hv.w, w3, fmaf(hv.z, w2,
                 fmaf(hv.y, w1, fmaf(hv.x, w0, acc[m]))));
      }
    }
    __syncthreads();
    #pragma unroll
    for (int m = 0; m < 64; ++m)
      h[m * 256 + tid] = LN2 * softplus_hat(acc[m] * LOG2E);
    __syncthreads();
  }
  {
    const int m = tid >> 2, qq = tid & 3;
    const float* wv = Wout + (s << 8);
    float sum = 0.f;
    for (int i = 0; i < 16; ++i) {
      int kk = (qq << 6) + ((((tid & 15) + i) << 2) & 63);
      float4v hv = *(const float4v*)&h[m * 256 + kk];
      sum += hv.x * wv[kk] + hv.y * wv[kk + 1] + hv.z * wv[kk + 2] + hv.w * wv[kk + 3];
    }
    red[tid] = sum;
    __syncthreads();
    if (tid < 64)
      out[(m0 + tid) * 8 + s] =
          red[tid * 4] + red[tid * 4 + 1] + red[tid * 4 + 2] + red[tid * 4 + 3] + bout[s];
  }
}

extern "C" void kernel_launch(void* const* d_in, const int* in_sizes, int n_in,
                              void* d_out, int out_size, void* d_ws, size_t ws_size,
                              hipStream_t stream) {
  const float* coords = (const float*)d_in[0];
  const float* W0     = (const float*)d_in[1];
  const float* b0     = (const float*)d_in[2];
  const float* Wh     = (const float*)d_in[3];
  const float* bh     = (const float*)d_in[4];
  const float* Wout   = (const float*)d_in[5];
  const float* bout   = (const float*)d_in[6];
  float* out = (float*)d_out;

  const size_t WT_BYTES = (size_t)8 * 4 * 256 * 256 * 2;   // 4 MiB bf16 slabs
  if (ws_size >= WT_BYTES) {
    unsigned short* Wt = (unsigned short*)d_ws;
    convert_wh<<<8192, 256, 0, stream>>>(Wh, Wt);
    series_mlp<<<dim3(25000), dim3(256), 0, stream>>>(
        coords, W0, b0, bh, Wout, bout, Wt, out);
  } else {
    series_mlp_slow<<<dim3(3125, 8), dim3(256), 0, stream>>>(
        coords, W0, b0, Wh, bh, Wout, bout, out);
  }
  // second tuple output: echo coords
  hipMemcpyAsync(out + (size_t)200000 * 8, coords,
                 (size_t)200000 * 3 * sizeof(float),
                 hipMemcpyDeviceToDevice, stream);
}